// Round 13
// baseline (129.808 us; speedup 1.0000x reference)
//
#include <hip/hip_runtime.h>
#include <math.h>

#define HD     64
#define NPIX   9216
#define B4     4
#define NQ     (B4 * NPIX)
#define K9     9
#define SSL    8              // sample slices (288 keys each -> keys 0..2303)
#define ZS     16             // gate key-split
#define KQZ    (NPIX / ZS)    // 576 keys per gate block
#define KTG    64             // gate LDS tile keys
#define NTG    (KQZ / KTG)    // 9
#define KTS    32             // sample LDS tile keys
#define NTS    9              // 288 keys per sample slice
#define DGATE  13.0f
#define CAP    96

typedef __attribute__((ext_vector_type(8)))  short bf16x8;
typedef __attribute__((ext_vector_type(16))) float f32x16;
typedef unsigned short ushort_t;
typedef unsigned long long u64;

__device__ __forceinline__ ushort_t f2bf(float x) {
  unsigned u = __float_as_uint(x);
  unsigned r = (u + 0x7fffu + ((u >> 16) & 1u)) >> 16;   // RNE
  return (ushort_t)r;
}

// ---- prep: transpose [b][d][n]->[b][n][d]; z=0: Qbf(x8)+Cnt=0; z=1: Kbf+Kt; z=2: Vt
__global__ __launch_bounds__(256) void prep_kernel(
    const float* __restrict__ qg, const float* __restrict__ kg,
    const float* __restrict__ vg,
    ushort_t* __restrict__ Qbf, ushort_t* __restrict__ Kbf,
    float* __restrict__ Kt, float* __restrict__ Vt, int* __restrict__ Cnt) {
  __shared__ float Ts[64][65];
  const int b = blockIdx.y, n0 = blockIdx.x * 64, z = blockIdx.z;
  const float* src = (z == 0) ? qg : (z == 1) ? kg : vg;
  const int tid = threadIdx.x;
  if (z == 0 && b == 0) Cnt[blockIdx.x * 256 + tid] = 0;   // 144*256 = NQ exactly
  #pragma unroll
  for (int i = 0; i < 16; ++i) {
    const int idx = i * 256 + tid, c = idx >> 6, nl = idx & 63;
    Ts[c][nl] = src[((size_t)b * HD + c) * NPIX + n0 + nl];
  }
  __syncthreads();
  if (z == 0) {
    #pragma unroll
    for (int i = 0; i < 16; ++i) {
      const int idx = i * 256 + tid, nl = idx >> 6, d = idx & 63;
      Qbf[((size_t)b * NPIX + n0 + nl) * HD + d] = f2bf(Ts[d][nl] * 8.f);
    }
  } else if (z == 1) {
    #pragma unroll
    for (int i = 0; i < 16; ++i) {
      const int idx = i * 256 + tid, nl = idx >> 6, d = idx & 63;
      const float x = Ts[d][nl];
      const size_t o = ((size_t)b * NPIX + n0 + nl) * HD + d;
      Kbf[o] = f2bf(x); Kt[o] = x;
    }
  } else {
    #pragma unroll
    for (int i = 0; i < 16; ++i) {
      const int idx = i * 256 + tid, nl = idx >> 6, d = idx & 63;
      Vt[((size_t)b * NPIX + n0 + nl) * HD + d] = Ts[d][nl];
    }
  }
}

// ---------------- async global -> LDS (16B per lane, linear dest) ------------
__device__ __forceinline__ void gl_lds16(const void* g, void* l) {
  auto gp = reinterpret_cast<const unsigned int __attribute__((address_space(1)))*>(
      reinterpret_cast<uintptr_t>(g));
  auto lp = reinterpret_cast<unsigned int __attribute__((address_space(3)))*>(
      reinterpret_cast<uintptr_t>(l));
  __builtin_amdgcn_global_load_lds(gp, lp, 16, 0, 0);
}

// ==== sample: per-query max over keys [z*288, z*288+288); 32 q/wave ==========
__global__ __launch_bounds__(256, 8) void pass_sample(
    const ushort_t* __restrict__ Qbf, const ushort_t* __restrict__ Kbf,
    float* __restrict__ Pm) {
  __shared__ __align__(16) char SM[2][4096];   // 32 keys x 128B, double buffer

  const int tid = threadIdx.x;
  const int w = tid >> 6, l = tid & 63;
  const int lq = l & 31, hi = l >> 5, par = l & 7;
  const int b = blockIdx.y, qbase = blockIdx.x * 128, z = blockIdx.z;
  const int kbase = z * KTS * NTS;            // z*288
  const int qw = qbase + w * 32;
  const int qi = b * NPIX + qw + lq;

  // Q fragment (B operand): col = lane&31 = query, k = (lane>>5)*8 + e
  bf16x8 qf[4];
  {
    const size_t q0 = (size_t)qi * HD + hi * 8;
    #pragma unroll
    for (int i = 0; i < 4; ++i)
      qf[i] = *reinterpret_cast<const bf16x8*>(Qbf + q0 + i * 16);
  }

  const char* kB = reinterpret_cast<const char*>(Kbf + (size_t)b * NPIX * HD);
  const int sr = tid >> 3, sc = tid & 7;
  const int srcoff = sr * 128 + ((sc ^ (sr & 7)) << 4);
  const int hdst = w * 1024;
  int oi[4];
  #pragma unroll
  for (int i = 0; i < 4; ++i) oi[i] = lq * 128 + (((i * 2 + hi) ^ par) << 4);

  auto stage = [&](int tile, int nb) {
    const size_t toff = ((size_t)(kbase + tile * KTS)) * 128 + srcoff;
    gl_lds16(kB + toff, SM[nb] + hdst);
  };

  float m = -3.4e38f;
  stage(0, 0);
  __syncthreads();

  for (int t = 0; t < NTS; ++t) {
    const int cur = t & 1;
    if (t + 1 < NTS) stage(t + 1, cur ^ 1);
    const char* kt = SM[cur];

    f32x16 a = {0.f,0.f,0.f,0.f,0.f,0.f,0.f,0.f,0.f,0.f,0.f,0.f,0.f,0.f,0.f,0.f};
    #pragma unroll
    for (int i = 0; i < 4; ++i) {
      const bf16x8 av = *reinterpret_cast<const bf16x8*>(kt + oi[i]);
      a = __builtin_amdgcn_mfma_f32_32x32x16_bf16(av, qf[i], a, 0, 0, 0);
    }
    const float t0 = fmaxf(fmaxf(a[0],  a[1]),  a[2]);
    const float t1 = fmaxf(fmaxf(a[3],  a[4]),  a[5]);
    const float t2 = fmaxf(fmaxf(a[6],  a[7]),  a[8]);
    const float t3 = fmaxf(fmaxf(a[9],  a[10]), a[11]);
    const float t4 = fmaxf(fmaxf(a[12], a[13]), a[14]);
    m = fmaxf(m, fmaxf(fmaxf(fmaxf(t0, t1), t2), fmaxf(fmaxf(t3, t4), a[15])));
    __syncthreads();
  }

  m = fmaxf(m, __shfl_xor(m, 32, 64));     // combine the two k-halves
  if (l < 32) Pm[(size_t)z * NQ + qi] = m;
}

// ---- per-lane candidate shift-register buffer (8 x 16-bit local keys) -------
struct LB { u64 lo, hi; int cnt; };

__device__ __forceinline__ void flushLB(LB& b, int qi, int kbase,
                                        int* __restrict__ Cnt,
                                        unsigned* __restrict__ Cand) {
  if (b.cnt == 0) return;
  const int slot = atomicAdd(&Cnt[qi], b.cnt);
  for (int j = 0; j < b.cnt; ++j) {
    const int sh = 16 * j;
    const unsigned key = (sh < 64) ? (unsigned)((b.lo >> sh) & 0xFFFFull)
                                   : (unsigned)((b.hi >> (sh - 64)) & 0xFFFFull);
    if (slot + j < CAP)
      Cand[(size_t)qi * CAP + slot + j] = (unsigned)(kbase + (int)key);
  }
  b.lo = 0ull; b.hi = 0ull; b.cnt = 0;
}

__device__ __forceinline__ void pushLB(LB& b, unsigned key10, int qi, int kbase,
                                       int* __restrict__ Cnt,
                                       unsigned* __restrict__ Cand) {
  b.hi = (b.hi << 16) | (b.lo >> 48);
  b.lo = (b.lo << 16) | (u64)key10;
  if (++b.cnt == 8) flushLB(b, qi, kbase, Cnt, Cand);   // rare slow path
}

// ==== gate: 32x32 hi-only scores, 32 q/wave, register-buffered emits =========
__global__ __launch_bounds__(256, 8) void pass_gate(
    const ushort_t* __restrict__ Qbf, const ushort_t* __restrict__ Kbf,
    const float* __restrict__ Pm,
    int* __restrict__ Cnt, unsigned* __restrict__ Cand) {
  __shared__ __align__(16) char SM[2][8192];   // 64 keys x 128B, double buffer

  const int tid = threadIdx.x;
  const int w = tid >> 6, l = tid & 63;
  const int lq = l & 31, hi = l >> 5, par = l & 7;
  const int b = blockIdx.y, qbase = blockIdx.x * 128, z = blockIdx.z;
  const int kbase = z * KQZ;
  const int qw = qbase + w * 32;
  const int qi = b * NPIX + qw + lq;

  bf16x8 qf[4];
  {
    const size_t q0 = (size_t)qi * HD + hi * 8;
    #pragma unroll
    for (int i = 0; i < 4; ++i)
      qf[i] = *reinterpret_cast<const bf16x8*>(Qbf + q0 + i * 16);
  }

  float tau = -3.4e38f;
  #pragma unroll
  for (int s = 0; s < SSL; ++s) tau = fmaxf(tau, Pm[(size_t)s * NQ + qi]);
  float gt = tau - DGATE;

  const char* kB = reinterpret_cast<const char*>(Kbf + (size_t)b * NPIX * HD);
  const int sr = tid >> 3, sc = tid & 7;
  const int srcoff = sr * 128 + ((sc ^ (sr & 7)) << 4);
  const int hdst = w * 1024;
  int oi[4];
  #pragma unroll
  for (int i = 0; i < 4; ++i) oi[i] = lq * 128 + (((i * 2 + hi) ^ par) << 4);

  auto stage = [&](int tile, int nb) {
    const size_t toff = ((size_t)(kbase + tile * KTG)) * 128 + srcoff;
    gl_lds16(kB + toff, SM[nb] + hdst);
    gl_lds16(kB + toff + 4096, SM[nb] + 4096 + hdst);
  };

  LB lb = {0ull, 0ull, 0};

  stage(0, 0);
  __syncthreads();

  for (int t = 0; t < NTG; ++t) {
    const int cur = t & 1;
    if (t + 1 < NTG) stage(t + 1, cur ^ 1);
    const char* kt = SM[cur];

    #pragma unroll
    for (int g = 0; g < 2; ++g) {
      const int gbyte = g * 4096;
      f32x16 a = {0.f,0.f,0.f,0.f,0.f,0.f,0.f,0.f,0.f,0.f,0.f,0.f,0.f,0.f,0.f,0.f};
      #pragma unroll
      for (int i = 0; i < 4; ++i) {
        const bf16x8 av = *reinterpret_cast<const bf16x8*>(kt + gbyte + oi[i]);
        a = __builtin_amdgcn_mfma_f32_32x32x16_bf16(av, qf[i], a, 0, 0, 0);
      }
      // 16-score max tree (max3-friendly)
      const float t0 = fmaxf(fmaxf(a[0],  a[1]),  a[2]);
      const float t1 = fmaxf(fmaxf(a[3],  a[4]),  a[5]);
      const float t2 = fmaxf(fmaxf(a[6],  a[7]),  a[8]);
      const float t3 = fmaxf(fmaxf(a[9],  a[10]), a[11]);
      const float t4 = fmaxf(fmaxf(a[12], a[13]), a[14]);
      const float s16 = fmaxf(fmaxf(fmaxf(t0, t1), t2),
                              fmaxf(fmaxf(t3, t4), a[15]));
      const float old = gt;
      gt = fmaxf(old, s16 - DGATE);
      if (s16 > old) {                     // rare: near-record in this window
        const int kb = t * KTG + g * 32 + 4 * hi;   // local (in-slice) key base
        #pragma unroll
        for (int e = 0; e < 16; ++e) {
          const int off = (e >> 2) * 8 + (e & 3);   // reg -> key row offset
          if (a[e] > gt) pushLB(lb, (unsigned)(kb + off), qi, kbase, Cnt, Cand);
        }
      }
    }
    __syncthreads();
  }

  flushLB(lb, qi, kbase, Cnt, Cand);
}

// ==== merge: wave-parallel exact rescore + top-9 extraction + V gather =======
// 2 queries per wave (32 lanes each), 8 queries per block.
__global__ __launch_bounds__(256) void merge_v(
    const unsigned* __restrict__ Cand, const int* __restrict__ Cnt,
    const float* __restrict__ qg, const float* __restrict__ Kt,
    const float* __restrict__ Vt, float* __restrict__ Og) {
  __shared__ float Qs[8][HD];
  const int tid = threadIdx.x, b = blockIdx.y;
  const int nbase = blockIdx.x * 8;

  {
    const int ql = tid >> 5, d0 = (tid & 31) * 2;
    const int n = nbase + ql;
    Qs[ql][d0]     = 8.f * qg[((size_t)b * HD + d0) * NPIX + n];
    Qs[ql][d0 + 1] = 8.f * qg[((size_t)b * HD + d0 + 1) * NPIX + n];
  }
  __syncthreads();

  const int wid = tid >> 6, lane = tid & 63;
  const int half = lane >> 5, l32 = lane & 31;
  const int ql = wid * 2 + half;
  const int n  = nbase + ql;
  const int qi = b * NPIX + n;
  const int c  = min(Cnt[qi], CAP);

  u64 p[3] = {0ull, 0ull, 0ull};
  #pragma unroll
  for (int r = 0; r < 3; ++r) {
    const int j = r * 32 + l32;
    if (j < c) {
      const int idx = (int)Cand[(size_t)qi * CAP + j];
      const float4* kr = reinterpret_cast<const float4*>(
          Kt + ((size_t)b * NPIX + idx) * HD);
      float acc = 0.f;
      #pragma unroll
      for (int u = 0; u < 16; ++u) {
        const float4 qx = *reinterpret_cast<const float4*>(&Qs[ql][u * 4]);
        const float4 kx = kr[u];
        acc = fmaf(qx.x, kx.x, acc); acc = fmaf(qx.y, kx.y, acc);
        acc = fmaf(qx.z, kx.z, acc); acc = fmaf(qx.w, kx.w, acc);
      }
      unsigned ub = __float_as_uint(acc);
      ub = (ub & 0x80000000u) ? ~ub : (ub | 0x80000000u);
      p[r] = ((u64)ub << 14) | (u64)(unsigned)(0x3FFF - idx);
    }
  }

  float mv[K9]; int mi[K9];
  #pragma unroll
  for (int r = 0; r < K9; ++r) {
    u64 bst = p[0] > p[1] ? p[0] : p[1];
    bst = bst > p[2] ? bst : p[2];
    #pragma unroll
    for (int m = 1; m < 32; m <<= 1) {
      const u64 o = __shfl_xor(bst, m, 32);
      bst = (o > bst) ? o : bst;
    }
    if (bst != 0ull) {
      #pragma unroll
      for (int s = 0; s < 3; ++s) if (p[s] == bst) p[s] = 0ull;
      const int idx = 0x3FFF - (int)(bst & 0x3FFFull);
      unsigned ub = (unsigned)(bst >> 14);
      ub = (ub & 0x80000000u) ? (ub ^ 0x80000000u) : ~ub;
      mv[r] = __uint_as_float(ub);
      mi[r] = idx;
    } else {
      mv[r] = -3.4e38f; mi[r] = 0;
    }
  }

  const float mmax = mv[0];
  float wr[K9]; float wsum = 0.f;
  #pragma unroll
  for (int r = 0; r < K9; ++r) { wr[r] = expf(mv[r] - mmax); wsum += wr[r]; }
  const float inv = 1.f / wsum;

  float2 o2 = make_float2(0.f, 0.f);
  #pragma unroll
  for (int r = 0; r < K9; ++r) {
    const float w2 = wr[r] * inv;
    const float2 v2 = *reinterpret_cast<const float2*>(
        Vt + ((size_t)b * NPIX + mi[r]) * HD + l32 * 2);
    o2.x = fmaf(w2, v2.x, o2.x);
    o2.y = fmaf(w2, v2.y, o2.y);
  }
  *reinterpret_cast<float2*>(Og + ((size_t)b * NPIX + n) * HD + l32 * 2) = o2;
}

// ================= launch =====================================================
extern "C" void kernel_launch(void* const* d_in, const int* in_sizes, int n_in,
                              void* d_out, int out_size, void* d_ws, size_t ws_size,
                              hipStream_t stream) {
  const float* q = (const float*)d_in[0];
  const float* k = (const float*)d_in[1];
  const float* v = (const float*)d_in[2];
  float* o = (float*)d_out;

  const size_t asz = (size_t)B4 * NPIX * HD;
  ushort_t* Qbf = (ushort_t*)d_ws;                    // 4.72 MB
  ushort_t* Kbf = Qbf + asz;                          // 4.72 MB
  float*    Kt  = (float*)(Kbf + asz);                // 9.44 MB
  float*    Vt  = Kt + asz;                           // 9.44 MB
  float*    Pm  = Vt + asz;                           // 1.18 MB [SSL][qi]
  int*      Ct  = (int*)(Pm + (size_t)SSL * NQ);      // 0.15 MB
  unsigned* Cd  = (unsigned*)(Ct + NQ);               // 14.2 MB [qi][CAP]

  prep_kernel<<<dim3(NPIX / 64, B4, 3), 256, 0, stream>>>(q, k, v, Qbf, Kbf, Kt, Vt, Ct);
  pass_sample<<<dim3(NPIX / 128, B4, SSL), 256, 0, stream>>>(Qbf, Kbf, Pm);
  pass_gate<<<dim3(NPIX / 128, B4, ZS), 256, 0, stream>>>(Qbf, Kbf, Pm, Ct, Cd);
  merge_v<<<dim3(NPIX / 8, B4), 256, 0, stream>>>(Cd, Ct, q, Kt, Vt, o);
}

// Round 16
// 127.840 us; speedup vs baseline: 1.0154x; 1.0154x over previous
//
#include <hip/hip_runtime.h>
#include <math.h>

#define HD     64
#define NPIX   9216
#define B4     4
#define NQ     (B4 * NPIX)
#define K9     9
#define SSL    8              // sample slices (288 keys each -> keys 0..2303)
#define ZS     16             // gate key-split
#define KQZ    (NPIX / ZS)    // 576 keys per gate block
#define KTL    32             // keys per LDS tile (1-wave blocks)
#define NTG    (KQZ / KTL)    // 18 tiles (gate)
#define NTS    9              // 288/32 tiles (sample)
#define DGATE  13.0f
#define CAP    96

typedef __attribute__((ext_vector_type(8)))  short bf16x8;
typedef __attribute__((ext_vector_type(16))) float f32x16;
typedef unsigned short ushort_t;
typedef unsigned long long u64;

__device__ __forceinline__ ushort_t f2bf(float x) {
  unsigned u = __float_as_uint(x);
  unsigned r = (u + 0x7fffu + ((u >> 16) & 1u)) >> 16;   // RNE
  return (ushort_t)r;
}

// ---- prep: transpose [b][d][n]->[b][n][d]; z=0: Qbf(x8)+Cnt=0; z=1: Kbf+Kt; z=2: Vt
__global__ __launch_bounds__(256) void prep_kernel(
    const float* __restrict__ qg, const float* __restrict__ kg,
    const float* __restrict__ vg,
    ushort_t* __restrict__ Qbf, ushort_t* __restrict__ Kbf,
    float* __restrict__ Kt, float* __restrict__ Vt, int* __restrict__ Cnt) {
  __shared__ float Ts[64][65];
  const int b = blockIdx.y, n0 = blockIdx.x * 64, z = blockIdx.z;
  const float* src = (z == 0) ? qg : (z == 1) ? kg : vg;
  const int tid = threadIdx.x;
  if (z == 0 && b == 0) Cnt[blockIdx.x * 256 + tid] = 0;   // 144*256 = NQ exactly
  #pragma unroll
  for (int i = 0; i < 16; ++i) {
    const int idx = i * 256 + tid, c = idx >> 6, nl = idx & 63;
    Ts[c][nl] = src[((size_t)b * HD + c) * NPIX + n0 + nl];
  }
  __syncthreads();
  if (z == 0) {
    #pragma unroll
    for (int i = 0; i < 16; ++i) {
      const int idx = i * 256 + tid, nl = idx >> 6, d = idx & 63;
      Qbf[((size_t)b * NPIX + n0 + nl) * HD + d] = f2bf(Ts[d][nl] * 8.f);
    }
  } else if (z == 1) {
    #pragma unroll
    for (int i = 0; i < 16; ++i) {
      const int idx = i * 256 + tid, nl = idx >> 6, d = idx & 63;
      const float x = Ts[d][nl];
      const size_t o = ((size_t)b * NPIX + n0 + nl) * HD + d;
      Kbf[o] = f2bf(x); Kt[o] = x;
    }
  } else {
    #pragma unroll
    for (int i = 0; i < 16; ++i) {
      const int idx = i * 256 + tid, nl = idx >> 6, d = idx & 63;
      Vt[((size_t)b * NPIX + n0 + nl) * HD + d] = Ts[d][nl];
    }
  }
}

// ---------------- async global -> LDS (16B per lane, linear dest) ------------
__device__ __forceinline__ void gl_lds16(const void* g, void* l) {
  auto gp = reinterpret_cast<const unsigned int __attribute__((address_space(1)))*>(
      reinterpret_cast<uintptr_t>(g));
  auto lp = reinterpret_cast<unsigned int __attribute__((address_space(3)))*>(
      reinterpret_cast<uintptr_t>(l));
  __builtin_amdgcn_global_load_lds(gp, lp, 16, 0, 0);
}

// ---- per-lane candidate shift-register buffer (8 x 16-bit local keys) -------
struct LB { u64 lo, hi; int cnt; };

__device__ __forceinline__ void flushLB(LB& b, int qi, int kbase,
                                        int* __restrict__ Cnt,
                                        unsigned* __restrict__ Cand) {
  if (b.cnt == 0) return;
  const int slot = atomicAdd(&Cnt[qi], b.cnt);
  for (int j = 0; j < b.cnt; ++j) {
    const int sh = 16 * j;
    const unsigned key = (sh < 64) ? (unsigned)((b.lo >> sh) & 0xFFFFull)
                                   : (unsigned)((b.hi >> (sh - 64)) & 0xFFFFull);
    if (slot + j < CAP)
      Cand[(size_t)qi * CAP + slot + j] = (unsigned)(kbase + (int)key);
  }
  b.lo = 0ull; b.hi = 0ull; b.cnt = 0;
}

__device__ __forceinline__ void pushLB(LB& b, unsigned key10, int qi, int kbase,
                                       int* __restrict__ Cnt,
                                       unsigned* __restrict__ Cand) {
  b.hi = (b.hi << 16) | (b.lo >> 48);
  b.lo = (b.lo << 16) | (u64)key10;
  if (++b.cnt == 8) flushLB(b, qi, kbase, Cnt, Cand);   // rare slow path
}

// ==== sample: 1-wave block, 64 q (2 chains), keys [z*288, z*288+288) =========
__global__ __launch_bounds__(64, 4) void pass_sample(
    const ushort_t* __restrict__ Qbf, const ushort_t* __restrict__ Kbf,
    float* __restrict__ Pm) {
  __shared__ __align__(16) char SM[2][4096];   // private: 32 keys x 128B, dbuf

  const int l = threadIdx.x;
  const int lq = l & 31, hi = l >> 5, par = lq & 7;
  const int b = blockIdx.y, qw = blockIdx.x * 64, z = blockIdx.z;
  const int kbase = z * KTL * NTS;            // z*288
  const int qi0 = b * NPIX + qw + lq;
  const int qi1 = qi0 + 32;

  bf16x8 qf0[4], qf1[4];
  {
    const size_t q0 = (size_t)qi0 * HD + hi * 8;
    const size_t q1 = (size_t)qi1 * HD + hi * 8;
    #pragma unroll
    for (int i = 0; i < 4; ++i) {
      qf0[i] = *reinterpret_cast<const bf16x8*>(Qbf + q0 + i * 16);
      qf1[i] = *reinterpret_cast<const bf16x8*>(Qbf + q1 + i * 16);
    }
  }

  const char* kB = reinterpret_cast<const char*>(Kbf + (size_t)b * NPIX * HD);
  // staging: 64 lanes cover 8 rows x 8 col-blocks; 4 calls cover 32 rows
  const int sr = l >> 3, sc = l & 7;
  const int srcoff = sr * 128 + ((sc ^ sr) << 4);
  int oi[4];
  #pragma unroll
  for (int i = 0; i < 4; ++i) oi[i] = lq * 128 + (((i * 2 + hi) ^ par) << 4);

  auto stage = [&](int tile, int nb) {
    const size_t toff = ((size_t)(kbase + tile * KTL)) * 128 + srcoff;
    #pragma unroll
    for (int p = 0; p < 4; ++p)
      gl_lds16(kB + toff + p * 1024, SM[nb] + p * 1024);
  };

  float m0 = -3.4e38f, m1 = -3.4e38f;
  stage(0, 0);

  for (int t = 0; t < NTS; ++t) {
    const int cur = t & 1;
    if (t + 1 < NTS) stage(t + 1, cur ^ 1);
    __syncthreads();   // compiler-managed drain: all LDS-DMA landed
    const char* kt = SM[cur];

    f32x16 a0 = {0.f,0.f,0.f,0.f,0.f,0.f,0.f,0.f,0.f,0.f,0.f,0.f,0.f,0.f,0.f,0.f};
    f32x16 a1 = {0.f,0.f,0.f,0.f,0.f,0.f,0.f,0.f,0.f,0.f,0.f,0.f,0.f,0.f,0.f,0.f};
    #pragma unroll
    for (int i = 0; i < 4; ++i) {
      const bf16x8 av = *reinterpret_cast<const bf16x8*>(kt + oi[i]);
      a0 = __builtin_amdgcn_mfma_f32_32x32x16_bf16(av, qf0[i], a0, 0, 0, 0);
      a1 = __builtin_amdgcn_mfma_f32_32x32x16_bf16(av, qf1[i], a1, 0, 0, 0);
    }
    {
      const float t0 = fmaxf(fmaxf(a0[0],  a0[1]),  a0[2]);
      const float t1 = fmaxf(fmaxf(a0[3],  a0[4]),  a0[5]);
      const float t2 = fmaxf(fmaxf(a0[6],  a0[7]),  a0[8]);
      const float t3 = fmaxf(fmaxf(a0[9],  a0[10]), a0[11]);
      const float t4 = fmaxf(fmaxf(a0[12], a0[13]), a0[14]);
      m0 = fmaxf(m0, fmaxf(fmaxf(fmaxf(t0, t1), t2),
                           fmaxf(fmaxf(t3, t4), a0[15])));
    }
    {
      const float t0 = fmaxf(fmaxf(a1[0],  a1[1]),  a1[2]);
      const float t1 = fmaxf(fmaxf(a1[3],  a1[4]),  a1[5]);
      const float t2 = fmaxf(fmaxf(a1[6],  a1[7]),  a1[8]);
      const float t3 = fmaxf(fmaxf(a1[9],  a1[10]), a1[11]);
      const float t4 = fmaxf(fmaxf(a1[12], a1[13]), a1[14]);
      m1 = fmaxf(m1, fmaxf(fmaxf(fmaxf(t0, t1), t2),
                           fmaxf(fmaxf(t3, t4), a1[15])));
    }
    __syncthreads();   // reads done before next tile's DMA overwrites buffer
  }

  m0 = fmaxf(m0, __shfl_xor(m0, 32, 64));    // combine the two k-halves
  m1 = fmaxf(m1, __shfl_xor(m1, 32, 64));
  if (l < 32) {
    Pm[(size_t)z * NQ + qi0] = m0;
    Pm[(size_t)z * NQ + qi1] = m1;
  }
}

// ==== gate: 1-wave block, 64 q (2 chains), tau-seeded gate, syncthreads ======
__global__ __launch_bounds__(64, 4) void pass_gate(
    const ushort_t* __restrict__ Qbf, const ushort_t* __restrict__ Kbf,
    const float* __restrict__ Pm,
    int* __restrict__ Cnt, unsigned* __restrict__ Cand) {
  __shared__ __align__(16) char SM[2][4096];   // private: 32 keys x 128B, dbuf

  const int l = threadIdx.x;
  const int lq = l & 31, hi = l >> 5, par = lq & 7;
  const int b = blockIdx.y, qw = blockIdx.x * 64, z = blockIdx.z;
  const int kbase = z * KQZ;
  const int qi0 = b * NPIX + qw + lq;
  const int qi1 = qi0 + 32;

  bf16x8 qf0[4], qf1[4];
  {
    const size_t q0 = (size_t)qi0 * HD + hi * 8;
    const size_t q1 = (size_t)qi1 * HD + hi * 8;
    #pragma unroll
    for (int i = 0; i < 4; ++i) {
      qf0[i] = *reinterpret_cast<const bf16x8*>(Qbf + q0 + i * 16);
      qf1[i] = *reinterpret_cast<const bf16x8*>(Qbf + q1 + i * 16);
    }
  }

  float tau0 = -3.4e38f, tau1 = -3.4e38f;
  #pragma unroll
  for (int s = 0; s < SSL; ++s) {
    tau0 = fmaxf(tau0, Pm[(size_t)s * NQ + qi0]);
    tau1 = fmaxf(tau1, Pm[(size_t)s * NQ + qi1]);
  }
  float gt0 = tau0 - DGATE, gt1 = tau1 - DGATE;

  const char* kB = reinterpret_cast<const char*>(Kbf + (size_t)b * NPIX * HD);
  const int sr = l >> 3, sc = l & 7;
  const int srcoff = sr * 128 + ((sc ^ sr) << 4);
  int oi[4];
  #pragma unroll
  for (int i = 0; i < 4; ++i) oi[i] = lq * 128 + (((i * 2 + hi) ^ par) << 4);

  auto stage = [&](int tile, int nb) {
    const size_t toff = ((size_t)(kbase + tile * KTL)) * 128 + srcoff;
    #pragma unroll
    for (int p = 0; p < 4; ++p)
      gl_lds16(kB + toff + p * 1024, SM[nb] + p * 1024);
  };

  LB lb0 = {0ull, 0ull, 0}, lb1 = {0ull, 0ull, 0};

  auto chain = [&](const f32x16& a, float& gt, LB& lb, int qi, int kb) {
    const float t0 = fmaxf(fmaxf(a[0],  a[1]),  a[2]);
    const float t1 = fmaxf(fmaxf(a[3],  a[4]),  a[5]);
    const float t2 = fmaxf(fmaxf(a[6],  a[7]),  a[8]);
    const float t3 = fmaxf(fmaxf(a[9],  a[10]), a[11]);
    const float t4 = fmaxf(fmaxf(a[12], a[13]), a[14]);
    const float s16 = fmaxf(fmaxf(fmaxf(t0, t1), t2),
                            fmaxf(fmaxf(t3, t4), a[15]));
    const float old = gt;
    gt = fmaxf(old, s16 - DGATE);
    if (s16 > old) {                     // rare: near-record in this window
      #pragma unroll
      for (int e = 0; e < 16; ++e) {
        const int off = (e >> 2) * 8 + (e & 3);   // reg -> key row offset
        if (a[e] > gt) pushLB(lb, (unsigned)(kb + off), qi, kbase, Cnt, Cand);
      }
    }
  };

  stage(0, 0);

  for (int t = 0; t < NTG; ++t) {
    const int cur = t & 1;
    if (t + 1 < NTG) stage(t + 1, cur ^ 1);
    __syncthreads();   // compiler-managed drain: all LDS-DMA landed
    const char* kt = SM[cur];

    f32x16 a0 = {0.f,0.f,0.f,0.f,0.f,0.f,0.f,0.f,0.f,0.f,0.f,0.f,0.f,0.f,0.f,0.f};
    f32x16 a1 = {0.f,0.f,0.f,0.f,0.f,0.f,0.f,0.f,0.f,0.f,0.f,0.f,0.f,0.f,0.f,0.f};
    #pragma unroll
    for (int i = 0; i < 4; ++i) {
      const bf16x8 av = *reinterpret_cast<const bf16x8*>(kt + oi[i]);
      a0 = __builtin_amdgcn_mfma_f32_32x32x16_bf16(av, qf0[i], a0, 0, 0, 0);
      a1 = __builtin_amdgcn_mfma_f32_32x32x16_bf16(av, qf1[i], a1, 0, 0, 0);
    }
    const int kb = t * KTL + 4 * hi;     // local (in-slice) key base
    chain(a0, gt0, lb0, qi0, kb);
    chain(a1, gt1, lb1, qi1, kb);
    __syncthreads();   // reads done before next tile's DMA overwrites buffer
  }

  flushLB(lb0, qi0, kbase, Cnt, Cand);
  flushLB(lb1, qi1, kbase, Cnt, Cand);
}

// ==== merge: wave-parallel exact rescore + top-9 extraction + V gather =======
// 2 queries per wave (32 lanes each), 8 queries per block.
__global__ __launch_bounds__(256) void merge_v(
    const unsigned* __restrict__ Cand, const int* __restrict__ Cnt,
    const float* __restrict__ qg, const float* __restrict__ Kt,
    const float* __restrict__ Vt, float* __restrict__ Og) {
  __shared__ float Qs[8][HD];
  const int tid = threadIdx.x, b = blockIdx.y;
  const int nbase = blockIdx.x * 8;

  {
    const int ql = tid >> 5, d0 = (tid & 31) * 2;
    const int n = nbase + ql;
    Qs[ql][d0]     = 8.f * qg[((size_t)b * HD + d0) * NPIX + n];
    Qs[ql][d0 + 1] = 8.f * qg[((size_t)b * HD + d0 + 1) * NPIX + n];
  }
  __syncthreads();

  const int wid = tid >> 6, lane = tid & 63;
  const int half = lane >> 5, l32 = lane & 31;
  const int ql = wid * 2 + half;
  const int n  = nbase + ql;
  const int qi = b * NPIX + n;
  const int c  = min(Cnt[qi], CAP);

  u64 p[3] = {0ull, 0ull, 0ull};
  #pragma unroll
  for (int r = 0; r < 3; ++r) {
    const int j = r * 32 + l32;
    if (j < c) {
      const int idx = (int)Cand[(size_t)qi * CAP + j];
      const float4* kr = reinterpret_cast<const float4*>(
          Kt + ((size_t)b * NPIX + idx) * HD);
      float acc = 0.f;
      #pragma unroll
      for (int u = 0; u < 16; ++u) {
        const float4 qx = *reinterpret_cast<const float4*>(&Qs[ql][u * 4]);
        const float4 kx = kr[u];
        acc = fmaf(qx.x, kx.x, acc); acc = fmaf(qx.y, kx.y, acc);
        acc = fmaf(qx.z, kx.z, acc); acc = fmaf(qx.w, kx.w, acc);
      }
      unsigned ub = __float_as_uint(acc);
      ub = (ub & 0x80000000u) ? ~ub : (ub | 0x80000000u);
      p[r] = ((u64)ub << 14) | (u64)(unsigned)(0x3FFF - idx);
    }
  }

  float mv[K9]; int mi[K9];
  #pragma unroll
  for (int r = 0; r < K9; ++r) {
    u64 bst = p[0] > p[1] ? p[0] : p[1];
    bst = bst > p[2] ? bst : p[2];
    #pragma unroll
    for (int m = 1; m < 32; m <<= 1) {
      const u64 o = __shfl_xor(bst, m, 32);
      bst = (o > bst) ? o : bst;
    }
    if (bst != 0ull) {
      #pragma unroll
      for (int s = 0; s < 3; ++s) if (p[s] == bst) p[s] = 0ull;
      const int idx = 0x3FFF - (int)(bst & 0x3FFFull);
      unsigned ub = (unsigned)(bst >> 14);
      ub = (ub & 0x80000000u) ? (ub ^ 0x80000000u) : ~ub;
      mv[r] = __uint_as_float(ub);
      mi[r] = idx;
    } else {
      mv[r] = -3.4e38f; mi[r] = 0;
    }
  }

  const float mmax = mv[0];
  float wr[K9]; float wsum = 0.f;
  #pragma unroll
  for (int r = 0; r < K9; ++r) { wr[r] = expf(mv[r] - mmax); wsum += wr[r]; }
  const float inv = 1.f / wsum;

  float2 o2 = make_float2(0.f, 0.f);
  #pragma unroll
  for (int r = 0; r < K9; ++r) {
    const float w2 = wr[r] * inv;
    const float2 v2 = *reinterpret_cast<const float2*>(
        Vt + ((size_t)b * NPIX + mi[r]) * HD + l32 * 2);
    o2.x = fmaf(w2, v2.x, o2.x);
    o2.y = fmaf(w2, v2.y, o2.y);
  }
  *reinterpret_cast<float2*>(Og + ((size_t)b * NPIX + n) * HD + l32 * 2) = o2;
}

// ================= launch =====================================================
extern "C" void kernel_launch(void* const* d_in, const int* in_sizes, int n_in,
                              void* d_out, int out_size, void* d_ws, size_t ws_size,
                              hipStream_t stream) {
  const float* q = (const float*)d_in[0];
  const float* k = (const float*)d_in[1];
  const float* v = (const float*)d_in[2];
  float* o = (float*)d_out;

  const size_t asz = (size_t)B4 * NPIX * HD;
  ushort_t* Qbf = (ushort_t*)d_ws;                    // 4.72 MB
  ushort_t* Kbf = Qbf + asz;                          // 4.72 MB
  float*    Kt  = (float*)(Kbf + asz);                // 9.44 MB
  float*    Vt  = Kt + asz;                           // 9.44 MB
  float*    Pm  = Vt + asz;                           // 1.18 MB [SSL][qi]
  int*      Ct  = (int*)(Pm + (size_t)SSL * NQ);      // 0.15 MB
  unsigned* Cd  = (unsigned*)(Ct + NQ);               // 14.2 MB [qi][CAP]

  prep_kernel<<<dim3(NPIX / 64, B4, 3), 256, 0, stream>>>(q, k, v, Qbf, Kbf, Kt, Vt, Ct);
  pass_sample<<<dim3(NPIX / 64, B4, SSL), 64, 0, stream>>>(Qbf, Kbf, Pm);
  pass_gate<<<dim3(NPIX / 64, B4, ZS), 64, 0, stream>>>(Qbf, Kbf, Pm, Ct, Cd);
  merge_v<<<dim3(NPIX / 8, B4), 256, 0, stream>>>(Cd, Ct, q, Kt, Vt, o);
}

// Round 17
// 123.585 us; speedup vs baseline: 1.0504x; 1.0344x over previous
//
#include <hip/hip_runtime.h>
#include <math.h>

#define HD     64
#define NPIX   9216
#define B4     4
#define NQ     (B4 * NPIX)
#define K9     9
#define SSL    8              // sample slices (288 keys each -> keys 0..2303)
#define ZS     16             // gate key-split
#define KQZ    (NPIX / ZS)    // 576 keys per gate block
#define KTL    32             // keys per LDS tile (1-wave blocks)
#define NTG    (KQZ / KTL)    // 18 tiles (gate)
#define NTS    9              // 288/32 tiles (sample)
#define DGATE  13.0f
#define CAP    96

typedef __attribute__((ext_vector_type(8)))  short bf16x8;
typedef __attribute__((ext_vector_type(16))) float f32x16;
typedef unsigned short ushort_t;
typedef unsigned long long u64;

__device__ __forceinline__ ushort_t f2bf(float x) {
  unsigned u = __float_as_uint(x);
  unsigned r = (u + 0x7fffu + ((u >> 16) & 1u)) >> 16;   // RNE
  return (ushort_t)r;
}

// ---- prep: transpose [b][d][n]->[b][n][d]; z=0: Qbf(x8)+Cnt=0; z=1: Kbf+Kt; z=2: Vt
__global__ __launch_bounds__(256) void prep_kernel(
    const float* __restrict__ qg, const float* __restrict__ kg,
    const float* __restrict__ vg,
    ushort_t* __restrict__ Qbf, ushort_t* __restrict__ Kbf,
    float* __restrict__ Kt, float* __restrict__ Vt, int* __restrict__ Cnt) {
  __shared__ float Ts[64][65];
  const int b = blockIdx.y, n0 = blockIdx.x * 64, z = blockIdx.z;
  const float* src = (z == 0) ? qg : (z == 1) ? kg : vg;
  const int tid = threadIdx.x;
  if (z == 0 && b == 0) Cnt[blockIdx.x * 256 + tid] = 0;   // 144*256 = NQ exactly
  #pragma unroll
  for (int i = 0; i < 16; ++i) {
    const int idx = i * 256 + tid, c = idx >> 6, nl = idx & 63;
    Ts[c][nl] = src[((size_t)b * HD + c) * NPIX + n0 + nl];
  }
  __syncthreads();
  if (z == 0) {
    #pragma unroll
    for (int i = 0; i < 16; ++i) {
      const int idx = i * 256 + tid, nl = idx >> 6, d = idx & 63;
      Qbf[((size_t)b * NPIX + n0 + nl) * HD + d] = f2bf(Ts[d][nl] * 8.f);
    }
  } else if (z == 1) {
    #pragma unroll
    for (int i = 0; i < 16; ++i) {
      const int idx = i * 256 + tid, nl = idx >> 6, d = idx & 63;
      const float x = Ts[d][nl];
      const size_t o = ((size_t)b * NPIX + n0 + nl) * HD + d;
      Kbf[o] = f2bf(x); Kt[o] = x;
    }
  } else {
    #pragma unroll
    for (int i = 0; i < 16; ++i) {
      const int idx = i * 256 + tid, nl = idx >> 6, d = idx & 63;
      Vt[((size_t)b * NPIX + n0 + nl) * HD + d] = Ts[d][nl];
    }
  }
}

// ---------------- async global -> LDS (16B per lane, linear dest) ------------
__device__ __forceinline__ void gl_lds16(const void* g, void* l) {
  auto gp = reinterpret_cast<const unsigned int __attribute__((address_space(1)))*>(
      reinterpret_cast<uintptr_t>(g));
  auto lp = reinterpret_cast<unsigned int __attribute__((address_space(3)))*>(
      reinterpret_cast<uintptr_t>(l));
  __builtin_amdgcn_global_load_lds(gp, lp, 16, 0, 0);
}

// ---- per-lane candidate shift-register buffer (8 x 16-bit local keys) -------
struct LB { u64 lo, hi; int cnt; };

__device__ __forceinline__ void flushLB(LB& b, int qi, int kbase,
                                        int* __restrict__ Cnt,
                                        unsigned* __restrict__ Cand) {
  if (b.cnt == 0) return;
  const int slot = atomicAdd(&Cnt[qi], b.cnt);
  for (int j = 0; j < b.cnt; ++j) {
    const int sh = 16 * j;
    const unsigned key = (sh < 64) ? (unsigned)((b.lo >> sh) & 0xFFFFull)
                                   : (unsigned)((b.hi >> (sh - 64)) & 0xFFFFull);
    if (slot + j < CAP)
      Cand[(size_t)qi * CAP + slot + j] = (unsigned)(kbase + (int)key);
  }
  b.lo = 0ull; b.hi = 0ull; b.cnt = 0;
}

__device__ __forceinline__ void pushLB(LB& b, unsigned key10, int qi, int kbase,
                                       int* __restrict__ Cnt,
                                       unsigned* __restrict__ Cand) {
  b.hi = (b.hi << 16) | (b.lo >> 48);
  b.lo = (b.lo << 16) | (u64)key10;
  if (++b.cnt == 8) flushLB(b, qi, kbase, Cnt, Cand);   // rare slow path
}

// ==== sample: 1-wave block, 64 q (2 chains), keys [z*288, z*288+288) =========
__global__ __launch_bounds__(64, 4) void pass_sample(
    const ushort_t* __restrict__ Qbf, const ushort_t* __restrict__ Kbf,
    float* __restrict__ Pm) {
  __shared__ __align__(16) char SM[2][4096];   // private: 32 keys x 128B, dbuf

  const int l = threadIdx.x;
  const int lq = l & 31, hi = l >> 5, par = lq & 7;
  const int b = blockIdx.y, qw = blockIdx.x * 64, z = blockIdx.z;
  const int kbase = z * KTL * NTS;            // z*288
  const int qi0 = b * NPIX + qw + lq;
  const int qi1 = qi0 + 32;

  bf16x8 qf0[4], qf1[4];
  {
    const size_t q0 = (size_t)qi0 * HD + hi * 8;
    const size_t q1 = (size_t)qi1 * HD + hi * 8;
    #pragma unroll
    for (int i = 0; i < 4; ++i) {
      qf0[i] = *reinterpret_cast<const bf16x8*>(Qbf + q0 + i * 16);
      qf1[i] = *reinterpret_cast<const bf16x8*>(Qbf + q1 + i * 16);
    }
  }

  const char* kB = reinterpret_cast<const char*>(Kbf + (size_t)b * NPIX * HD);
  // staging: 64 lanes cover 8 rows x 8 col-blocks; 4 calls cover 32 rows
  const int sr = l >> 3, sc = l & 7;
  const int srcoff = sr * 128 + ((sc ^ sr) << 4);
  int oi[4];
  #pragma unroll
  for (int i = 0; i < 4; ++i) oi[i] = lq * 128 + (((i * 2 + hi) ^ par) << 4);

  auto stage = [&](int tile, int nb) {
    const size_t toff = ((size_t)(kbase + tile * KTL)) * 128 + srcoff;
    #pragma unroll
    for (int p = 0; p < 4; ++p)
      gl_lds16(kB + toff + p * 1024, SM[nb] + p * 1024);
  };

  float m0 = -3.4e38f, m1 = -3.4e38f;
  stage(0, 0);
  __syncthreads();           // tile 0 landed (no overlap for tile 0 only)

  for (int t = 0; t < NTS; ++t) {
    const int cur = t & 1;
    if (t + 1 < NTS) stage(t + 1, cur ^ 1);   // DMA flies under compute below
    const char* kt = SM[cur];

    f32x16 a0 = {0.f,0.f,0.f,0.f,0.f,0.f,0.f,0.f,0.f,0.f,0.f,0.f,0.f,0.f,0.f,0.f};
    f32x16 a1 = {0.f,0.f,0.f,0.f,0.f,0.f,0.f,0.f,0.f,0.f,0.f,0.f,0.f,0.f,0.f,0.f};
    #pragma unroll
    for (int i = 0; i < 4; ++i) {
      const bf16x8 av = *reinterpret_cast<const bf16x8*>(kt + oi[i]);
      a0 = __builtin_amdgcn_mfma_f32_32x32x16_bf16(av, qf0[i], a0, 0, 0, 0);
      a1 = __builtin_amdgcn_mfma_f32_32x32x16_bf16(av, qf1[i], a1, 0, 0, 0);
    }
    {
      const float t0 = fmaxf(fmaxf(a0[0],  a0[1]),  a0[2]);
      const float t1 = fmaxf(fmaxf(a0[3],  a0[4]),  a0[5]);
      const float t2 = fmaxf(fmaxf(a0[6],  a0[7]),  a0[8]);
      const float t3 = fmaxf(fmaxf(a0[9],  a0[10]), a0[11]);
      const float t4 = fmaxf(fmaxf(a0[12], a0[13]), a0[14]);
      m0 = fmaxf(m0, fmaxf(fmaxf(fmaxf(t0, t1), t2),
                           fmaxf(fmaxf(t3, t4), a0[15])));
    }
    {
      const float t0 = fmaxf(fmaxf(a1[0],  a1[1]),  a1[2]);
      const float t1 = fmaxf(fmaxf(a1[3],  a1[4]),  a1[5]);
      const float t2 = fmaxf(fmaxf(a1[6],  a1[7]),  a1[8]);
      const float t3 = fmaxf(fmaxf(a1[9],  a1[10]), a1[11]);
      const float t4 = fmaxf(fmaxf(a1[12], a1[13]), a1[14]);
      m1 = fmaxf(m1, fmaxf(fmaxf(fmaxf(t0, t1), t2),
                           fmaxf(fmaxf(t3, t4), a1[15])));
    }
    __syncthreads();         // drain residue of DMA(t+1); reads of cur done
  }

  m0 = fmaxf(m0, __shfl_xor(m0, 32, 64));    // combine the two k-halves
  m1 = fmaxf(m1, __shfl_xor(m1, 32, 64));
  if (l < 32) {
    Pm[(size_t)z * NQ + qi0] = m0;
    Pm[(size_t)z * NQ + qi1] = m1;
  }
}

// ==== gate: 1-wave block, 64 q (2 chains), tau-seeded gate, rotated loop =====
__global__ __launch_bounds__(64, 4) void pass_gate(
    const ushort_t* __restrict__ Qbf, const ushort_t* __restrict__ Kbf,
    const float* __restrict__ Pm,
    int* __restrict__ Cnt, unsigned* __restrict__ Cand) {
  __shared__ __align__(16) char SM[2][4096];   // private: 32 keys x 128B, dbuf

  const int l = threadIdx.x;
  const int lq = l & 31, hi = l >> 5, par = lq & 7;
  const int b = blockIdx.y, qw = blockIdx.x * 64, z = blockIdx.z;
  const int kbase = z * KQZ;
  const int qi0 = b * NPIX + qw + lq;
  const int qi1 = qi0 + 32;

  bf16x8 qf0[4], qf1[4];
  {
    const size_t q0 = (size_t)qi0 * HD + hi * 8;
    const size_t q1 = (size_t)qi1 * HD + hi * 8;
    #pragma unroll
    for (int i = 0; i < 4; ++i) {
      qf0[i] = *reinterpret_cast<const bf16x8*>(Qbf + q0 + i * 16);
      qf1[i] = *reinterpret_cast<const bf16x8*>(Qbf + q1 + i * 16);
    }
  }

  float tau0 = -3.4e38f, tau1 = -3.4e38f;
  #pragma unroll
  for (int s = 0; s < SSL; ++s) {
    tau0 = fmaxf(tau0, Pm[(size_t)s * NQ + qi0]);
    tau1 = fmaxf(tau1, Pm[(size_t)s * NQ + qi1]);
  }
  float gt0 = tau0 - DGATE, gt1 = tau1 - DGATE;

  const char* kB = reinterpret_cast<const char*>(Kbf + (size_t)b * NPIX * HD);
  const int sr = l >> 3, sc = l & 7;
  const int srcoff = sr * 128 + ((sc ^ sr) << 4);
  int oi[4];
  #pragma unroll
  for (int i = 0; i < 4; ++i) oi[i] = lq * 128 + (((i * 2 + hi) ^ par) << 4);

  auto stage = [&](int tile, int nb) {
    const size_t toff = ((size_t)(kbase + tile * KTL)) * 128 + srcoff;
    #pragma unroll
    for (int p = 0; p < 4; ++p)
      gl_lds16(kB + toff + p * 1024, SM[nb] + p * 1024);
  };

  LB lb0 = {0ull, 0ull, 0}, lb1 = {0ull, 0ull, 0};

  auto chain = [&](const f32x16& a, float& gt, LB& lb, int qi, int kb) {
    const float t0 = fmaxf(fmaxf(a[0],  a[1]),  a[2]);
    const float t1 = fmaxf(fmaxf(a[3],  a[4]),  a[5]);
    const float t2 = fmaxf(fmaxf(a[6],  a[7]),  a[8]);
    const float t3 = fmaxf(fmaxf(a[9],  a[10]), a[11]);
    const float t4 = fmaxf(fmaxf(a[12], a[13]), a[14]);
    const float s16 = fmaxf(fmaxf(fmaxf(t0, t1), t2),
                            fmaxf(fmaxf(t3, t4), a[15]));
    const float old = gt;
    gt = fmaxf(old, s16 - DGATE);
    if (s16 > old) {                     // rare: near-record in this window
      #pragma unroll
      for (int e = 0; e < 16; ++e) {
        const int off = (e >> 2) * 8 + (e & 3);   // reg -> key row offset
        if (a[e] > gt) pushLB(lb, (unsigned)(kb + off), qi, kbase, Cnt, Cand);
      }
    }
  };

  stage(0, 0);
  __syncthreads();           // tile 0 landed (no overlap for tile 0 only)

  for (int t = 0; t < NTG; ++t) {
    const int cur = t & 1;
    if (t + 1 < NTG) stage(t + 1, cur ^ 1);   // DMA flies under compute below
    const char* kt = SM[cur];

    f32x16 a0 = {0.f,0.f,0.f,0.f,0.f,0.f,0.f,0.f,0.f,0.f,0.f,0.f,0.f,0.f,0.f,0.f};
    f32x16 a1 = {0.f,0.f,0.f,0.f,0.f,0.f,0.f,0.f,0.f,0.f,0.f,0.f,0.f,0.f,0.f,0.f};
    #pragma unroll
    for (int i = 0; i < 4; ++i) {
      const bf16x8 av = *reinterpret_cast<const bf16x8*>(kt + oi[i]);
      a0 = __builtin_amdgcn_mfma_f32_32x32x16_bf16(av, qf0[i], a0, 0, 0, 0);
      a1 = __builtin_amdgcn_mfma_f32_32x32x16_bf16(av, qf1[i], a1, 0, 0, 0);
    }
    const int kb = t * KTL + 4 * hi;     // local (in-slice) key base
    chain(a0, gt0, lb0, qi0, kb);
    chain(a1, gt1, lb1, qi1, kb);
    __syncthreads();         // drain residue of DMA(t+1); reads of cur done
  }

  flushLB(lb0, qi0, kbase, Cnt, Cand);
  flushLB(lb1, qi1, kbase, Cnt, Cand);
}

// ==== merge: wave-parallel exact rescore + top-9 extraction + V gather =======
// 2 queries per wave (32 lanes each), 8 queries per block.
__global__ __launch_bounds__(256) void merge_v(
    const unsigned* __restrict__ Cand, const int* __restrict__ Cnt,
    const float* __restrict__ qg, const float* __restrict__ Kt,
    const float* __restrict__ Vt, float* __restrict__ Og) {
  __shared__ float Qs[8][HD];
  const int tid = threadIdx.x, b = blockIdx.y;
  const int nbase = blockIdx.x * 8;

  {
    const int ql = tid >> 5, d0 = (tid & 31) * 2;
    const int n = nbase + ql;
    Qs[ql][d0]     = 8.f * qg[((size_t)b * HD + d0) * NPIX + n];
    Qs[ql][d0 + 1] = 8.f * qg[((size_t)b * HD + d0 + 1) * NPIX + n];
  }
  __syncthreads();

  const int wid = tid >> 6, lane = tid & 63;
  const int half = lane >> 5, l32 = lane & 31;
  const int ql = wid * 2 + half;
  const int n  = nbase + ql;
  const int qi = b * NPIX + n;
  const int c  = min(Cnt[qi], CAP);

  u64 p[3] = {0ull, 0ull, 0ull};
  #pragma unroll
  for (int r = 0; r < 3; ++r) {
    const int j = r * 32 + l32;
    if (j < c) {
      const int idx = (int)Cand[(size_t)qi * CAP + j];
      const float4* kr = reinterpret_cast<const float4*>(
          Kt + ((size_t)b * NPIX + idx) * HD);
      float acc = 0.f;
      #pragma unroll
      for (int u = 0; u < 16; ++u) {
        const float4 qx = *reinterpret_cast<const float4*>(&Qs[ql][u * 4]);
        const float4 kx = kr[u];
        acc = fmaf(qx.x, kx.x, acc); acc = fmaf(qx.y, kx.y, acc);
        acc = fmaf(qx.z, kx.z, acc); acc = fmaf(qx.w, kx.w, acc);
      }
      unsigned ub = __float_as_uint(acc);
      ub = (ub & 0x80000000u) ? ~ub : (ub | 0x80000000u);
      p[r] = ((u64)ub << 14) | (u64)(unsigned)(0x3FFF - idx);
    }
  }

  float mv[K9]; int mi[K9];
  #pragma unroll
  for (int r = 0; r < K9; ++r) {
    u64 bst = p[0] > p[1] ? p[0] : p[1];
    bst = bst > p[2] ? bst : p[2];
    #pragma unroll
    for (int m = 1; m < 32; m <<= 1) {
      const u64 o = __shfl_xor(bst, m, 32);
      bst = (o > bst) ? o : bst;
    }
    if (bst != 0ull) {
      #pragma unroll
      for (int s = 0; s < 3; ++s) if (p[s] == bst) p[s] = 0ull;
      const int idx = 0x3FFF - (int)(bst & 0x3FFFull);
      unsigned ub = (unsigned)(bst >> 14);
      ub = (ub & 0x80000000u) ? (ub ^ 0x80000000u) : ~ub;
      mv[r] = __uint_as_float(ub);
      mi[r] = idx;
    } else {
      mv[r] = -3.4e38f; mi[r] = 0;
    }
  }

  const float mmax = mv[0];
  float wr[K9]; float wsum = 0.f;
  #pragma unroll
  for (int r = 0; r < K9; ++r) { wr[r] = expf(mv[r] - mmax); wsum += wr[r]; }
  const float inv = 1.f / wsum;

  float2 o2 = make_float2(0.f, 0.f);
  #pragma unroll
  for (int r = 0; r < K9; ++r) {
    const float w2 = wr[r] * inv;
    const float2 v2 = *reinterpret_cast<const float2*>(
        Vt + ((size_t)b * NPIX + mi[r]) * HD + l32 * 2);
    o2.x = fmaf(w2, v2.x, o2.x);
    o2.y = fmaf(w2, v2.y, o2.y);
  }
  *reinterpret_cast<float2*>(Og + ((size_t)b * NPIX + n) * HD + l32 * 2) = o2;
}

// ================= launch =====================================================
extern "C" void kernel_launch(void* const* d_in, const int* in_sizes, int n_in,
                              void* d_out, int out_size, void* d_ws, size_t ws_size,
                              hipStream_t stream) {
  const float* q = (const float*)d_in[0];
  const float* k = (const float*)d_in[1];
  const float* v = (const float*)d_in[2];
  float* o = (float*)d_out;

  const size_t asz = (size_t)B4 * NPIX * HD;
  ushort_t* Qbf = (ushort_t*)d_ws;                    // 4.72 MB
  ushort_t* Kbf = Qbf + asz;                          // 4.72 MB
  float*    Kt  = (float*)(Kbf + asz);                // 9.44 MB
  float*    Vt  = Kt + asz;                           // 9.44 MB
  float*    Pm  = Vt + asz;                           // 1.18 MB [SSL][qi]
  int*      Ct  = (int*)(Pm + (size_t)SSL * NQ);      // 0.15 MB
  unsigned* Cd  = (unsigned*)(Ct + NQ);               // 14.2 MB [qi][CAP]

  prep_kernel<<<dim3(NPIX / 64, B4, 3), 256, 0, stream>>>(q, k, v, Qbf, Kbf, Kt, Vt, Ct);
  pass_sample<<<dim3(NPIX / 64, B4, SSL), 64, 0, stream>>>(Qbf, Kbf, Pm);
  pass_gate<<<dim3(NPIX / 64, B4, ZS), 64, 0, stream>>>(Qbf, Kbf, Pm, Ct, Cd);
  merge_v<<<dim3(NPIX / 8, B4), 256, 0, stream>>>(Cd, Ct, q, Kt, Vt, o);
}

// Round 18
// 122.609 us; speedup vs baseline: 1.0587x; 1.0080x over previous
//
#include <hip/hip_runtime.h>
#include <math.h>

#define HD     64
#define NPIX   9216
#define B4     4
#define NQ     (B4 * NPIX)
#define K9     9
#define NCH    3              // acc chains per wave (96 queries)
#define QPB    (32 * NCH)     // 96 queries per block
#define SSL    8              // sample slices (288 keys each -> keys 0..2303)
#define ZS     16             // gate key-split
#define KQZ    (NPIX / ZS)    // 576 keys per gate block
#define KTL    32             // keys per LDS tile (1-wave blocks)
#define NTG    (KQZ / KTL)    // 18 tiles (gate)
#define NTS    9              // 288/32 tiles (sample)
#define DGATE  13.0f
#define CAP    96

typedef __attribute__((ext_vector_type(8)))  short bf16x8;
typedef __attribute__((ext_vector_type(16))) float f32x16;
typedef unsigned short ushort_t;
typedef unsigned long long u64;

__device__ __forceinline__ ushort_t f2bf(float x) {
  unsigned u = __float_as_uint(x);
  unsigned r = (u + 0x7fffu + ((u >> 16) & 1u)) >> 16;   // RNE
  return (ushort_t)r;
}

// ---- prep: transpose [b][d][n]->[b][n][d]; z=0: Qbf(x8)+Cnt=0; z=1: Kbf+Kt; z=2: Vt
__global__ __launch_bounds__(256) void prep_kernel(
    const float* __restrict__ qg, const float* __restrict__ kg,
    const float* __restrict__ vg,
    ushort_t* __restrict__ Qbf, ushort_t* __restrict__ Kbf,
    float* __restrict__ Kt, float* __restrict__ Vt, int* __restrict__ Cnt) {
  __shared__ float Ts[64][65];
  const int b = blockIdx.y, n0 = blockIdx.x * 64, z = blockIdx.z;
  const float* src = (z == 0) ? qg : (z == 1) ? kg : vg;
  const int tid = threadIdx.x;
  if (z == 0 && b == 0) Cnt[blockIdx.x * 256 + tid] = 0;   // 144*256 = NQ exactly
  #pragma unroll
  for (int i = 0; i < 16; ++i) {
    const int idx = i * 256 + tid, c = idx >> 6, nl = idx & 63;
    Ts[c][nl] = src[((size_t)b * HD + c) * NPIX + n0 + nl];
  }
  __syncthreads();
  if (z == 0) {
    #pragma unroll
    for (int i = 0; i < 16; ++i) {
      const int idx = i * 256 + tid, nl = idx >> 6, d = idx & 63;
      Qbf[((size_t)b * NPIX + n0 + nl) * HD + d] = f2bf(Ts[d][nl] * 8.f);
    }
  } else if (z == 1) {
    #pragma unroll
    for (int i = 0; i < 16; ++i) {
      const int idx = i * 256 + tid, nl = idx >> 6, d = idx & 63;
      const float x = Ts[d][nl];
      const size_t o = ((size_t)b * NPIX + n0 + nl) * HD + d;
      Kbf[o] = f2bf(x); Kt[o] = x;
    }
  } else {
    #pragma unroll
    for (int i = 0; i < 16; ++i) {
      const int idx = i * 256 + tid, nl = idx >> 6, d = idx & 63;
      Vt[((size_t)b * NPIX + n0 + nl) * HD + d] = Ts[d][nl];
    }
  }
}

// ---------------- async global -> LDS (16B per lane, linear dest) ------------
__device__ __forceinline__ void gl_lds16(const void* g, void* l) {
  auto gp = reinterpret_cast<const unsigned int __attribute__((address_space(1)))*>(
      reinterpret_cast<uintptr_t>(g));
  auto lp = reinterpret_cast<unsigned int __attribute__((address_space(3)))*>(
      reinterpret_cast<uintptr_t>(l));
  __builtin_amdgcn_global_load_lds(gp, lp, 16, 0, 0);
}

// ---- per-lane candidate shift-register buffer (8 x 16-bit local keys) -------
struct LB { u64 lo, hi; int cnt; };

__device__ __forceinline__ void flushLB(LB& b, int qi, int kbase,
                                        int* __restrict__ Cnt,
                                        unsigned* __restrict__ Cand) {
  if (b.cnt == 0) return;
  const int slot = atomicAdd(&Cnt[qi], b.cnt);
  for (int j = 0; j < b.cnt; ++j) {
    const int sh = 16 * j;
    const unsigned key = (sh < 64) ? (unsigned)((b.lo >> sh) & 0xFFFFull)
                                   : (unsigned)((b.hi >> (sh - 64)) & 0xFFFFull);
    if (slot + j < CAP)
      Cand[(size_t)qi * CAP + slot + j] = (unsigned)(kbase + (int)key);
  }
  b.lo = 0ull; b.hi = 0ull; b.cnt = 0;
}

__device__ __forceinline__ void pushLB(LB& b, unsigned key10, int qi, int kbase,
                                       int* __restrict__ Cnt,
                                       unsigned* __restrict__ Cand) {
  b.hi = (b.hi << 16) | (b.lo >> 48);
  b.lo = (b.lo << 16) | (u64)key10;
  if (++b.cnt == 8) flushLB(b, qi, kbase, Cnt, Cand);   // rare slow path
}

// ==== sample: 1-wave block, 96 q (3 chains), keys [z*288, z*288+288) =========
__global__ __launch_bounds__(64, 3) void pass_sample(
    const ushort_t* __restrict__ Qbf, const ushort_t* __restrict__ Kbf,
    float* __restrict__ Pm) {
  __shared__ __align__(16) char SM[2][4096];   // private: 32 keys x 128B, dbuf

  const int l = threadIdx.x;
  const int lq = l & 31, hi = l >> 5, par = lq & 7;
  const int b = blockIdx.y, qw = blockIdx.x * QPB, z = blockIdx.z;
  const int kbase = z * KTL * NTS;            // z*288

  int qi[NCH];
  bf16x8 qf[NCH][4];
  #pragma unroll
  for (int c = 0; c < NCH; ++c) {
    qi[c] = b * NPIX + qw + c * 32 + lq;
    const size_t q0 = (size_t)qi[c] * HD + hi * 8;
    #pragma unroll
    for (int i = 0; i < 4; ++i)
      qf[c][i] = *reinterpret_cast<const bf16x8*>(Qbf + q0 + i * 16);
  }

  const char* kB = reinterpret_cast<const char*>(Kbf + (size_t)b * NPIX * HD);
  const int sr = l >> 3, sc = l & 7;
  const int srcoff = sr * 128 + ((sc ^ sr) << 4);
  int oi[4];
  #pragma unroll
  for (int i = 0; i < 4; ++i) oi[i] = lq * 128 + (((i * 2 + hi) ^ par) << 4);

  auto stage = [&](int tile, int nb) {
    const size_t toff = ((size_t)(kbase + tile * KTL)) * 128 + srcoff;
    #pragma unroll
    for (int p = 0; p < 4; ++p)
      gl_lds16(kB + toff + p * 1024, SM[nb] + p * 1024);
  };

  float m[NCH];
  #pragma unroll
  for (int c = 0; c < NCH; ++c) m[c] = -3.4e38f;

  stage(0, 0);
  __syncthreads();           // tile 0 landed

  for (int t = 0; t < NTS; ++t) {
    const int cur = t & 1;
    if (t + 1 < NTS) stage(t + 1, cur ^ 1);   // DMA flies under compute below
    const char* kt = SM[cur];

    f32x16 a0 = {0.f,0.f,0.f,0.f,0.f,0.f,0.f,0.f,0.f,0.f,0.f,0.f,0.f,0.f,0.f,0.f};
    f32x16 a1 = a0, a2 = a0;
    #pragma unroll
    for (int i = 0; i < 4; ++i) {
      const bf16x8 av = *reinterpret_cast<const bf16x8*>(kt + oi[i]);
      a0 = __builtin_amdgcn_mfma_f32_32x32x16_bf16(av, qf[0][i], a0, 0, 0, 0);
      a1 = __builtin_amdgcn_mfma_f32_32x32x16_bf16(av, qf[1][i], a1, 0, 0, 0);
      a2 = __builtin_amdgcn_mfma_f32_32x32x16_bf16(av, qf[2][i], a2, 0, 0, 0);
    }
    {
      const float t0 = fmaxf(fmaxf(a0[0],  a0[1]),  a0[2]);
      const float t1 = fmaxf(fmaxf(a0[3],  a0[4]),  a0[5]);
      const float t2 = fmaxf(fmaxf(a0[6],  a0[7]),  a0[8]);
      const float t3 = fmaxf(fmaxf(a0[9],  a0[10]), a0[11]);
      const float t4 = fmaxf(fmaxf(a0[12], a0[13]), a0[14]);
      m[0] = fmaxf(m[0], fmaxf(fmaxf(fmaxf(t0, t1), t2),
                               fmaxf(fmaxf(t3, t4), a0[15])));
    }
    {
      const float t0 = fmaxf(fmaxf(a1[0],  a1[1]),  a1[2]);
      const float t1 = fmaxf(fmaxf(a1[3],  a1[4]),  a1[5]);
      const float t2 = fmaxf(fmaxf(a1[6],  a1[7]),  a1[8]);
      const float t3 = fmaxf(fmaxf(a1[9],  a1[10]), a1[11]);
      const float t4 = fmaxf(fmaxf(a1[12], a1[13]), a1[14]);
      m[1] = fmaxf(m[1], fmaxf(fmaxf(fmaxf(t0, t1), t2),
                               fmaxf(fmaxf(t3, t4), a1[15])));
    }
    {
      const float t0 = fmaxf(fmaxf(a2[0],  a2[1]),  a2[2]);
      const float t1 = fmaxf(fmaxf(a2[3],  a2[4]),  a2[5]);
      const float t2 = fmaxf(fmaxf(a2[6],  a2[7]),  a2[8]);
      const float t3 = fmaxf(fmaxf(a2[9],  a2[10]), a2[11]);
      const float t4 = fmaxf(fmaxf(a2[12], a2[13]), a2[14]);
      m[2] = fmaxf(m[2], fmaxf(fmaxf(fmaxf(t0, t1), t2),
                               fmaxf(fmaxf(t3, t4), a2[15])));
    }
    __syncthreads();         // drain DMA(t+1) residue; reads of cur done
  }

  #pragma unroll
  for (int c = 0; c < NCH; ++c)
    m[c] = fmaxf(m[c], __shfl_xor(m[c], 32, 64));   // combine two k-halves
  if (l < 32) {
    #pragma unroll
    for (int c = 0; c < NCH; ++c)
      Pm[(size_t)z * NQ + qi[c]] = m[c];
  }
}

// ==== gate: 1-wave block, 96 q (3 chains), tau-seeded gate, rotated loop =====
__global__ __launch_bounds__(64, 3) void pass_gate(
    const ushort_t* __restrict__ Qbf, const ushort_t* __restrict__ Kbf,
    const float* __restrict__ Pm,
    int* __restrict__ Cnt, unsigned* __restrict__ Cand) {
  __shared__ __align__(16) char SM[2][4096];   // private: 32 keys x 128B, dbuf

  const int l = threadIdx.x;
  const int lq = l & 31, hi = l >> 5, par = lq & 7;
  const int b = blockIdx.y, qw = blockIdx.x * QPB, z = blockIdx.z;
  const int kbase = z * KQZ;

  int qi[NCH];
  bf16x8 qf[NCH][4];
  float gt[NCH];
  #pragma unroll
  for (int c = 0; c < NCH; ++c) {
    qi[c] = b * NPIX + qw + c * 32 + lq;
    const size_t q0 = (size_t)qi[c] * HD + hi * 8;
    #pragma unroll
    for (int i = 0; i < 4; ++i)
      qf[c][i] = *reinterpret_cast<const bf16x8*>(Qbf + q0 + i * 16);
    float tau = -3.4e38f;
    #pragma unroll
    for (int s = 0; s < SSL; ++s) tau = fmaxf(tau, Pm[(size_t)s * NQ + qi[c]]);
    gt[c] = tau - DGATE;
  }

  const char* kB = reinterpret_cast<const char*>(Kbf + (size_t)b * NPIX * HD);
  const int sr = l >> 3, sc = l & 7;
  const int srcoff = sr * 128 + ((sc ^ sr) << 4);
  int oi[4];
  #pragma unroll
  for (int i = 0; i < 4; ++i) oi[i] = lq * 128 + (((i * 2 + hi) ^ par) << 4);

  auto stage = [&](int tile, int nb) {
    const size_t toff = ((size_t)(kbase + tile * KTL)) * 128 + srcoff;
    #pragma unroll
    for (int p = 0; p < 4; ++p)
      gl_lds16(kB + toff + p * 1024, SM[nb] + p * 1024);
  };

  LB lb0 = {0ull, 0ull, 0}, lb1 = {0ull, 0ull, 0}, lb2 = {0ull, 0ull, 0};

  auto chain = [&](const f32x16& a, float& gtc, LB& lb, int qq, int kb) {
    const float t0 = fmaxf(fmaxf(a[0],  a[1]),  a[2]);
    const float t1 = fmaxf(fmaxf(a[3],  a[4]),  a[5]);
    const float t2 = fmaxf(fmaxf(a[6],  a[7]),  a[8]);
    const float t3 = fmaxf(fmaxf(a[9],  a[10]), a[11]);
    const float t4 = fmaxf(fmaxf(a[12], a[13]), a[14]);
    const float s16 = fmaxf(fmaxf(fmaxf(t0, t1), t2),
                            fmaxf(fmaxf(t3, t4), a[15]));
    const float old = gtc;
    gtc = fmaxf(old, s16 - DGATE);
    if (s16 > old) {                     // rare: near-record in this window
      #pragma unroll
      for (int e = 0; e < 16; ++e) {
        const int off = (e >> 2) * 8 + (e & 3);   // reg -> key row offset
        if (a[e] > gtc) pushLB(lb, (unsigned)(kb + off), qq, kbase, Cnt, Cand);
      }
    }
  };

  stage(0, 0);
  __syncthreads();           // tile 0 landed

  for (int t = 0; t < NTG; ++t) {
    const int cur = t & 1;
    if (t + 1 < NTG) stage(t + 1, cur ^ 1);   // DMA flies under compute below
    const char* kt = SM[cur];

    f32x16 a0 = {0.f,0.f,0.f,0.f,0.f,0.f,0.f,0.f,0.f,0.f,0.f,0.f,0.f,0.f,0.f,0.f};
    f32x16 a1 = a0, a2 = a0;
    #pragma unroll
    for (int i = 0; i < 4; ++i) {
      const bf16x8 av = *reinterpret_cast<const bf16x8*>(kt + oi[i]);
      a0 = __builtin_amdgcn_mfma_f32_32x32x16_bf16(av, qf[0][i], a0, 0, 0, 0);
      a1 = __builtin_amdgcn_mfma_f32_32x32x16_bf16(av, qf[1][i], a1, 0, 0, 0);
      a2 = __builtin_amdgcn_mfma_f32_32x32x16_bf16(av, qf[2][i], a2, 0, 0, 0);
    }
    const int kb = t * KTL + 4 * hi;     // local (in-slice) key base
    chain(a0, gt[0], lb0, qi[0], kb);
    chain(a1, gt[1], lb1, qi[1], kb);
    chain(a2, gt[2], lb2, qi[2], kb);
    __syncthreads();         // drain DMA(t+1) residue; reads of cur done
  }

  flushLB(lb0, qi[0], kbase, Cnt, Cand);
  flushLB(lb1, qi[1], kbase, Cnt, Cand);
  flushLB(lb2, qi[2], kbase, Cnt, Cand);
}

// ==== merge: wave-parallel exact rescore + top-9 extraction + V gather =======
// 2 queries per wave (32 lanes each), 8 queries per block.
__global__ __launch_bounds__(256) void merge_v(
    const unsigned* __restrict__ Cand, const int* __restrict__ Cnt,
    const float* __restrict__ qg, const float* __restrict__ Kt,
    const float* __restrict__ Vt, float* __restrict__ Og) {
  __shared__ float Qs[8][HD];
  const int tid = threadIdx.x, b = blockIdx.y;
  const int nbase = blockIdx.x * 8;

  {
    const int ql = tid >> 5, d0 = (tid & 31) * 2;
    const int n = nbase + ql;
    Qs[ql][d0]     = 8.f * qg[((size_t)b * HD + d0) * NPIX + n];
    Qs[ql][d0 + 1] = 8.f * qg[((size_t)b * HD + d0 + 1) * NPIX + n];
  }
  __syncthreads();

  const int wid = tid >> 6, lane = tid & 63;
  const int half = lane >> 5, l32 = lane & 31;
  const int ql = wid * 2 + half;
  const int n  = nbase + ql;
  const int qi = b * NPIX + n;
  const int c  = min(Cnt[qi], CAP);

  u64 p[3] = {0ull, 0ull, 0ull};
  #pragma unroll
  for (int r = 0; r < 3; ++r) {
    const int j = r * 32 + l32;
    if (j < c) {
      const int idx = (int)Cand[(size_t)qi * CAP + j];
      const float4* kr = reinterpret_cast<const float4*>(
          Kt + ((size_t)b * NPIX + idx) * HD);
      float acc = 0.f;
      #pragma unroll
      for (int u = 0; u < 16; ++u) {
        const float4 qx = *reinterpret_cast<const float4*>(&Qs[ql][u * 4]);
        const float4 kx = kr[u];
        acc = fmaf(qx.x, kx.x, acc); acc = fmaf(qx.y, kx.y, acc);
        acc = fmaf(qx.z, kx.z, acc); acc = fmaf(qx.w, kx.w, acc);
      }
      unsigned ub = __float_as_uint(acc);
      ub = (ub & 0x80000000u) ? ~ub : (ub | 0x80000000u);
      p[r] = ((u64)ub << 14) | (u64)(unsigned)(0x3FFF - idx);
    }
  }

  float mv[K9]; int mi[K9];
  #pragma unroll
  for (int r = 0; r < K9; ++r) {
    u64 bst = p[0] > p[1] ? p[0] : p[1];
    bst = bst > p[2] ? bst : p[2];
    #pragma unroll
    for (int m = 1; m < 32; m <<= 1) {
      const u64 o = __shfl_xor(bst, m, 32);
      bst = (o > bst) ? o : bst;
    }
    if (bst != 0ull) {
      #pragma unroll
      for (int s = 0; s < 3; ++s) if (p[s] == bst) p[s] = 0ull;
      const int idx = 0x3FFF - (int)(bst & 0x3FFFull);
      unsigned ub = (unsigned)(bst >> 14);
      ub = (ub & 0x80000000u) ? (ub ^ 0x80000000u) : ~ub;
      mv[r] = __uint_as_float(ub);
      mi[r] = idx;
    } else {
      mv[r] = -3.4e38f; mi[r] = 0;
    }
  }

  const float mmax = mv[0];
  float wr[K9]; float wsum = 0.f;
  #pragma unroll
  for (int r = 0; r < K9; ++r) { wr[r] = expf(mv[r] - mmax); wsum += wr[r]; }
  const float inv = 1.f / wsum;

  float2 o2 = make_float2(0.f, 0.f);
  #pragma unroll
  for (int r = 0; r < K9; ++r) {
    const float w2 = wr[r] * inv;
    const float2 v2 = *reinterpret_cast<const float2*>(
        Vt + ((size_t)b * NPIX + mi[r]) * HD + l32 * 2);
    o2.x = fmaf(w2, v2.x, o2.x);
    o2.y = fmaf(w2, v2.y, o2.y);
  }
  *reinterpret_cast<float2*>(Og + ((size_t)b * NPIX + n) * HD + l32 * 2) = o2;
}

// ================= launch =====================================================
extern "C" void kernel_launch(void* const* d_in, const int* in_sizes, int n_in,
                              void* d_out, int out_size, void* d_ws, size_t ws_size,
                              hipStream_t stream) {
  const float* q = (const float*)d_in[0];
  const float* k = (const float*)d_in[1];
  const float* v = (const float*)d_in[2];
  float* o = (float*)d_out;

  const size_t asz = (size_t)B4 * NPIX * HD;
  ushort_t* Qbf = (ushort_t*)d_ws;                    // 4.72 MB
  ushort_t* Kbf = Qbf + asz;                          // 4.72 MB
  float*    Kt  = (float*)(Kbf + asz);                // 9.44 MB
  float*    Vt  = Kt + asz;                           // 9.44 MB
  float*    Pm  = Vt + asz;                           // 1.18 MB [SSL][qi]
  int*      Ct  = (int*)(Pm + (size_t)SSL * NQ);      // 0.15 MB
  unsigned* Cd  = (unsigned*)(Ct + NQ);               // 14.2 MB [qi][CAP]

  prep_kernel<<<dim3(NPIX / 64, B4, 3), 256, 0, stream>>>(q, k, v, Qbf, Kbf, Kt, Vt, Ct);
  pass_sample<<<dim3(NPIX / QPB, B4, SSL), 64, 0, stream>>>(Qbf, Kbf, Pm);
  pass_gate<<<dim3(NPIX / QPB, B4, ZS), 64, 0, stream>>>(Qbf, Kbf, Pm, Ct, Cd);
  merge_v<<<dim3(NPIX / 8, B4), 256, 0, stream>>>(Cd, Ct, q, Kt, Vt, o);
}